// Round 3
// baseline (3856.388 us; speedup 1.0000x reference)
//
#include <hip/hip_runtime.h>
#include <math.h>

#define DIN  128
#define HC   128
#define NEG  0.2f

// ---------------------------------------------------------------------------
// CSR build
// ---------------------------------------------------------------------------
__global__ void hist_kernel(const int* __restrict__ ei, int E, int N,
                            int* __restrict__ counts) {
    int i = blockIdx.x * blockDim.x + threadIdx.x;
    int Etot = E + N;
    if (i >= Etot) return;
    int dst = (i < E) ? ei[E + i] : (i - E);
    if (dst < 0 || dst >= N) return;
    atomicAdd(&counts[dst], 1);
}

__global__ void scan_kernel(const int* __restrict__ counts,
                            int* __restrict__ rowptr,
                            int* __restrict__ cursor, int n) {
    __shared__ int wsum[16];
    int tid  = threadIdx.x;          // 1024 threads
    int lane = tid & 63, wid = tid >> 6;
    int running = 0;
    for (int base = 0; base < n; base += 1024) {
        int i = base + tid;
        int v = (i < n) ? counts[i] : 0;
        int x = v;
        #pragma unroll
        for (int off = 1; off < 64; off <<= 1) {
            int y = __shfl_up(x, off, 64);
            if (lane >= off) x += y;
        }
        if (lane == 63) wsum[wid] = x;
        __syncthreads();
        if (tid < 16) {
            int w = wsum[tid];
            #pragma unroll
            for (int off = 1; off < 16; off <<= 1) {
                int y = __shfl_up(w, off, 64);
                if (tid >= off) w += y;
            }
            wsum[tid] = w;
        }
        __syncthreads();
        int excl = running + (wid ? wsum[wid - 1] : 0) + (x - v);
        if (i < n) { rowptr[i] = excl; cursor[i] = excl; }
        running += wsum[15];
        __syncthreads();
    }
    if (tid == 0) rowptr[n] = running;
}

__global__ void scatter_kernel(const int* __restrict__ ei, int E, int N,
                               int* __restrict__ cursor,
                               int* __restrict__ esrc) {
    int i = blockIdx.x * blockDim.x + threadIdx.x;
    int Etot = E + N;
    if (i >= Etot) return;
    int src = (i < E) ? ei[i]     : (i - E);
    int dst = (i < E) ? ei[E + i] : (i - E);
    if (dst < 0 || dst >= N || src < 0 || src >= N) return;
    int pos = atomicAdd(&cursor[dst], 1);
    esrc[pos] = src;
}

// ---------------------------------------------------------------------------
// Single GEMM: out = X@W + b.  X:[n,128], W:[128,128] row-major.
// Grid (ceil(n/32), 2): blockIdx.y selects (Wl,bl,xl) or (Wr,br,xr).
// 32-row tile, 16 KB LDS, acc 4x4/thread -> low VGPR, high occupancy (TLP
// hides L2 W-load latency; prior fused version was 3 blocks/CU, 32% VALU).
// ---------------------------------------------------------------------------
__global__ __launch_bounds__(256) void gemm_one(
        const float* __restrict__ X,
        const float* __restrict__ Wl, const float* __restrict__ bl,
        const float* __restrict__ Wr, const float* __restrict__ br,
        float* __restrict__ xl, float* __restrict__ xr, int nrows) {
    const float* W = blockIdx.y ? Wr : Wl;
    const float* b = blockIdx.y ? br : bl;
    float*       O = blockIdx.y ? xr : xl;

    __shared__ float xs[32][128];
    int tid = threadIdx.x;
    int i0  = blockIdx.x * 32;

    #pragma unroll
    for (int it = 0; it < 4; ++it) {
        int f   = it * 256 + tid;          // float4 index within 32x128 tile
        int row = f >> 5, c4 = f & 31;
        float4 v = make_float4(0.f, 0.f, 0.f, 0.f);
        if (i0 + row < nrows)
            v = *(const float4*)&X[(size_t)(i0 + row) * 128 + c4 * 4];
        *(float4*)&xs[row][c4 * 4] = v;
    }
    __syncthreads();

    int ty = tid >> 5, tx = tid & 31;      // ty: 4-row group, tx: col/4
    float acc[4][4] = {{0}};

    for (int k = 0; k < 128; k += 4) {
        float4 w[4];
        #pragma unroll
        for (int kk = 0; kk < 4; ++kk)
            w[kk] = *(const float4*)&W[(size_t)(k + kk) * 128 + tx * 4];
        float4 a[4];
        #pragma unroll
        for (int r = 0; r < 4; ++r)
            a[r] = *(const float4*)&xs[ty * 4 + r][k];
        #pragma unroll
        for (int kk = 0; kk < 4; ++kk) {
            #pragma unroll
            for (int r = 0; r < 4; ++r) {
                float av = (kk == 0) ? a[r].x : (kk == 1) ? a[r].y
                         : (kk == 2) ? a[r].z : a[r].w;
                acc[r][0] += av * w[kk].x; acc[r][1] += av * w[kk].y;
                acc[r][2] += av * w[kk].z; acc[r][3] += av * w[kk].w;
            }
        }
    }

    float4 vb = *(const float4*)&b[tx * 4];
    #pragma unroll
    for (int r = 0; r < 4; ++r) {
        int row = i0 + ty * 4 + r;
        if (row >= nrows) continue;
        float4 o = make_float4(acc[r][0] + vb.x, acc[r][1] + vb.y,
                               acc[r][2] + vb.z, acc[r][3] + vb.w);
        *(float4*)&O[(size_t)row * 128 + tx * 4] = o;
    }
}

// ---------------------------------------------------------------------------
// Fused GATv2 aggregation, 8 edges in flight per wave.
// Wave = 1 node. Lanes: 8 groups x 8. Group g processes edges pbeg+g, +8...
// Lane (g, gl) holds channels [8*gl..8*gl+7] (head0) and [64+8*gl..] (head1).
// Independent online-softmax state per group; 3-level flash-merge at end.
// ---------------------------------------------------------------------------
__device__ __forceinline__ float lrelu(float v) {
    return v > 0.f ? v : NEG * v;
}
__device__ __forceinline__ float dot4(float4 a, float4 x, float4 t) {
    return lrelu(a.x + x.x) * t.x + lrelu(a.y + x.y) * t.y
         + lrelu(a.z + x.z) * t.z + lrelu(a.w + x.w) * t.w;
}
__device__ __forceinline__ void fma4(float4& acc, float sc, float p, float4 a) {
    acc.x = acc.x * sc + p * a.x;  acc.y = acc.y * sc + p * a.y;
    acc.z = acc.z * sc + p * a.z;  acc.w = acc.w * sc + p * a.w;
}
__device__ __forceinline__ float4 shfl4(float4 v, int off) {
    float4 r;
    r.x = __shfl_xor(v.x, off, 64); r.y = __shfl_xor(v.y, off, 64);
    r.z = __shfl_xor(v.z, off, 64); r.w = __shfl_xor(v.w, off, 64);
    return r;
}
__device__ __forceinline__ void merge4(float4& acc, float sa, float4 o, float sb) {
    acc.x = acc.x * sa + o.x * sb;  acc.y = acc.y * sa + o.y * sb;
    acc.z = acc.z * sa + o.z * sb;  acc.w = acc.w * sa + o.w * sb;
}

__global__ __launch_bounds__(256) void gat_aggregate(
        const float* __restrict__ xl, const float* __restrict__ xr,
        const int* __restrict__ rowptr, const int* __restrict__ esrc,
        const float* __restrict__ att, const float* __restrict__ bias,
        float* __restrict__ hout, int n, int do_relu) {
    int node = (int)((blockIdx.x * blockDim.x + threadIdx.x) >> 6);
    int lane = threadIdx.x & 63;
    if (node >= n) return;
    int g  = lane >> 3;      // 8 groups of 8 lanes
    int gl = lane & 7;
    int c0 = gl * 8;

    const float* xrp = &xr[(size_t)node * 128];
    float4 xr0a = *(const float4*)&xrp[c0],      xr0b = *(const float4*)&xrp[c0 + 4];
    float4 xr1a = *(const float4*)&xrp[64 + c0], xr1b = *(const float4*)&xrp[64 + c0 + 4];
    float4 at0a = *(const float4*)&att[c0],      at0b = *(const float4*)&att[c0 + 4];
    float4 at1a = *(const float4*)&att[64 + c0], at1b = *(const float4*)&att[64 + c0 + 4];

    float m0 = -1e30f, m1 = -1e30f, s0 = 0.f, s1 = 0.f;
    float4 acc0a = make_float4(0,0,0,0), acc0b = make_float4(0,0,0,0);
    float4 acc1a = make_float4(0,0,0,0), acc1b = make_float4(0,0,0,0);

    int pbeg = rowptr[node], pend = rowptr[node + 1];
    for (int p = pbeg + g; p < pend; p += 8) {
        int s = esrc[p];
        const float* xlp = &xl[(size_t)s * 128];
        float4 a0a = *(const float4*)&xlp[c0],      a0b = *(const float4*)&xlp[c0 + 4];
        float4 a1a = *(const float4*)&xlp[64 + c0], a1b = *(const float4*)&xlp[64 + c0 + 4];

        float t0 = dot4(a0a, xr0a, at0a) + dot4(a0b, xr0b, at0b);
        float t1 = dot4(a1a, xr1a, at1a) + dot4(a1b, xr1b, at1b);
        #pragma unroll
        for (int off = 1; off < 8; off <<= 1) {
            t0 += __shfl_xor(t0, off, 64);
            t1 += __shfl_xor(t1, off, 64);
        }

        float nm0 = fmaxf(m0, t0), nm1 = fmaxf(m1, t1);
        float sc0 = __expf(m0 - nm0), sc1 = __expf(m1 - nm1);
        float p0  = __expf(t0 - nm0), p1  = __expf(t1 - nm1);
        s0 = s0 * sc0 + p0;  s1 = s1 * sc1 + p1;
        fma4(acc0a, sc0, p0, a0a);  fma4(acc0b, sc0, p0, a0b);
        fma4(acc1a, sc1, p1, a1a);  fma4(acc1b, sc1, p1, a1b);
        m0 = nm0; m1 = nm1;
    }

    // flash-merge the 8 group states (xor 8, 16, 32)
    #pragma unroll
    for (int off = 8; off <= 32; off <<= 1) {
        float om0 = __shfl_xor(m0, off, 64), om1 = __shfl_xor(m1, off, 64);
        float os0 = __shfl_xor(s0, off, 64), os1 = __shfl_xor(s1, off, 64);
        float4 oa0a = shfl4(acc0a, off), oa0b = shfl4(acc0b, off);
        float4 oa1a = shfl4(acc1a, off), oa1b = shfl4(acc1b, off);

        float nm0 = fmaxf(m0, om0), nm1 = fmaxf(m1, om1);
        float sa0 = __expf(m0 - nm0),  sb0 = __expf(om0 - nm0);
        float sa1 = __expf(m1 - nm1),  sb1 = __expf(om1 - nm1);
        s0 = s0 * sa0 + os0 * sb0;  s1 = s1 * sa1 + os1 * sb1;
        merge4(acc0a, sa0, oa0a, sb0);  merge4(acc0b, sa0, oa0b, sb0);
        merge4(acc1a, sa1, oa1a, sb1);  merge4(acc1b, sa1, oa1b, sb1);
        m0 = nm0; m1 = nm1;
    }

    if (g == 0) {
        float inv = 1.f / s0;
        float4 vba = *(const float4*)&bias[c0], vbb = *(const float4*)&bias[c0 + 4];
        float4 oa = make_float4(acc0a.x * inv + vba.x, acc0a.y * inv + vba.y,
                                acc0a.z * inv + vba.z, acc0a.w * inv + vba.w);
        float4 ob = make_float4(acc0b.x * inv + vbb.x, acc0b.y * inv + vbb.y,
                                acc0b.z * inv + vbb.z, acc0b.w * inv + vbb.w);
        if (do_relu) {
            oa.x = fmaxf(oa.x, 0.f); oa.y = fmaxf(oa.y, 0.f);
            oa.z = fmaxf(oa.z, 0.f); oa.w = fmaxf(oa.w, 0.f);
            ob.x = fmaxf(ob.x, 0.f); ob.y = fmaxf(ob.y, 0.f);
            ob.z = fmaxf(ob.z, 0.f); ob.w = fmaxf(ob.w, 0.f);
        }
        *(float4*)&hout[(size_t)node * 128 + c0]     = oa;
        *(float4*)&hout[(size_t)node * 128 + c0 + 4] = ob;
    } else if (g == 1) {
        float inv = 1.f / s1;
        float4 vba = *(const float4*)&bias[64 + c0], vbb = *(const float4*)&bias[64 + c0 + 4];
        float4 oa = make_float4(acc1a.x * inv + vba.x, acc1a.y * inv + vba.y,
                                acc1a.z * inv + vba.z, acc1a.w * inv + vba.w);
        float4 ob = make_float4(acc1b.x * inv + vbb.x, acc1b.y * inv + vbb.y,
                                acc1b.z * inv + vbb.z, acc1b.w * inv + vbb.w);
        if (do_relu) {
            oa.x = fmaxf(oa.x, 0.f); oa.y = fmaxf(oa.y, 0.f);
            oa.z = fmaxf(oa.z, 0.f); oa.w = fmaxf(oa.w, 0.f);
            ob.x = fmaxf(ob.x, 0.f); ob.y = fmaxf(ob.y, 0.f);
            ob.z = fmaxf(ob.z, 0.f); ob.w = fmaxf(ob.w, 0.f);
        }
        *(float4*)&hout[(size_t)node * 128 + 64 + c0]     = oa;
        *(float4*)&hout[(size_t)node * 128 + 64 + c0 + 4] = ob;
    }
}

// ---------------------------------------------------------------------------
// Output linear: out = h @ Wout + bout.  Wout:[128,4] row-major.
// ---------------------------------------------------------------------------
__global__ __launch_bounds__(256) void out_linear(
        const float* __restrict__ h, const float* __restrict__ Wout,
        const float* __restrict__ bout, float* __restrict__ out, int n) {
    int node = (int)((blockIdx.x * blockDim.x + threadIdx.x) >> 6);
    int lane = threadIdx.x & 63;
    if (node >= n) return;
    float h0 = h[(size_t)node * 128 + lane];
    float h1 = h[(size_t)node * 128 + 64 + lane];
    float4 w0 = *(const float4*)&Wout[lane * 4];
    float4 w1 = *(const float4*)&Wout[(64 + lane) * 4];
    float p0 = h0 * w0.x + h1 * w1.x;
    float p1 = h0 * w0.y + h1 * w1.y;
    float p2 = h0 * w0.z + h1 * w1.z;
    float p3 = h0 * w0.w + h1 * w1.w;
    #pragma unroll
    for (int off = 32; off > 0; off >>= 1) {
        p0 += __shfl_xor(p0, off, 64);
        p1 += __shfl_xor(p1, off, 64);
        p2 += __shfl_xor(p2, off, 64);
        p3 += __shfl_xor(p3, off, 64);
    }
    if (lane == 0) {
        float4 o = make_float4(p0 + bout[0], p1 + bout[1],
                               p2 + bout[2], p3 + bout[3]);
        *(float4*)&out[(size_t)node * 4] = o;
    }
}

// ---------------------------------------------------------------------------
extern "C" void kernel_launch(void* const* d_in, const int* in_sizes, int n_in,
                              void* d_out, int out_size, void* d_ws,
                              size_t ws_size, hipStream_t stream) {
    const float* x    = (const float*)d_in[0];
    const int*   ei   = (const int*)  d_in[1];
    const float* W1l  = (const float*)d_in[2];
    const float* b1l  = (const float*)d_in[3];
    const float* W1r  = (const float*)d_in[4];
    const float* b1r  = (const float*)d_in[5];
    const float* att1 = (const float*)d_in[6];
    const float* bias1= (const float*)d_in[7];
    const float* W2l  = (const float*)d_in[8];
    const float* b2l  = (const float*)d_in[9];
    const float* W2r  = (const float*)d_in[10];
    const float* b2r  = (const float*)d_in[11];
    const float* att2 = (const float*)d_in[12];
    const float* bias2= (const float*)d_in[13];
    const float* W3l  = (const float*)d_in[14];
    const float* b3l  = (const float*)d_in[15];
    const float* W3r  = (const float*)d_in[16];
    const float* b3r  = (const float*)d_in[17];
    const float* att3 = (const float*)d_in[18];
    const float* bias3= (const float*)d_in[19];
    const float* Wout = (const float*)d_in[20];
    const float* bout = (const float*)d_in[21];

    int N    = in_sizes[0] / DIN;
    int E    = in_sizes[1] / 2;
    int Etot = E + N;

    float* h      = (float*)d_ws;
    float* xl     = h  + (size_t)N * HC;
    float* xr     = xl + (size_t)N * HC;
    int*   esrc   = (int*)(xr + (size_t)N * HC);
    int*   rowptr = esrc + Etot;
    int*   cursor = rowptr + (N + 1);
    int*   counts = cursor + N;

    hipMemsetAsync(counts, 0, (size_t)N * sizeof(int), stream);
    hist_kernel<<<(Etot + 255) / 256, 256, 0, stream>>>(ei, E, N, counts);
    scan_kernel<<<1, 1024, 0, stream>>>(counts, rowptr, cursor, N);
    scatter_kernel<<<(Etot + 255) / 256, 256, 0, stream>>>(ei, E, N, cursor, esrc);

    dim3 gemm_grid((N + 31) / 32, 2);
    int  agg_grid = (N + 3) / 4;

    gemm_one<<<gemm_grid, 256, 0, stream>>>(x, W1l, b1l, W1r, b1r, xl, xr, N);
    gat_aggregate<<<agg_grid, 256, 0, stream>>>(xl, xr, rowptr, esrc, att1, bias1, h, N, 1);
    gemm_one<<<gemm_grid, 256, 0, stream>>>(h, W2l, b2l, W2r, b2r, xl, xr, N);
    gat_aggregate<<<agg_grid, 256, 0, stream>>>(xl, xr, rowptr, esrc, att2, bias2, h, N, 1);
    gemm_one<<<gemm_grid, 256, 0, stream>>>(h, W3l, b3l, W3r, b3r, xl, xr, N);
    gat_aggregate<<<agg_grid, 256, 0, stream>>>(xl, xr, rowptr, esrc, att3, bias3, h, N, 1);
    out_linear<<<(N + 3) / 4, 256, 0, stream>>>(h, Wout, bout, (float*)d_out, N);
}

// Round 4
// 639.407 us; speedup vs baseline: 6.0312x; 6.0312x over previous
//
#include <hip/hip_runtime.h>
#include <math.h>

#define DIN  128
#define HC   128
#define NEG  0.2f

// ---------------------------------------------------------------------------
// CSR build
// ---------------------------------------------------------------------------
__global__ void hist_kernel(const int* __restrict__ ei, int E, int N,
                            int* __restrict__ counts) {
    int i = blockIdx.x * blockDim.x + threadIdx.x;
    int Etot = E + N;
    if (i >= Etot) return;
    int dst = (i < E) ? ei[E + i] : (i - E);
    if (dst < 0 || dst >= N) return;
    atomicAdd(&counts[dst], 1);
}

__global__ void scan_kernel(const int* __restrict__ counts,
                            int* __restrict__ rowptr,
                            int* __restrict__ cursor, int n) {
    __shared__ int wsum[16];
    int tid  = threadIdx.x;          // 1024 threads
    int lane = tid & 63, wid = tid >> 6;
    int running = 0;
    for (int base = 0; base < n; base += 1024) {
        int i = base + tid;
        int v = (i < n) ? counts[i] : 0;
        int x = v;
        #pragma unroll
        for (int off = 1; off < 64; off <<= 1) {
            int y = __shfl_up(x, off, 64);
            if (lane >= off) x += y;
        }
        if (lane == 63) wsum[wid] = x;
        __syncthreads();
        if (tid < 16) {
            int w = wsum[tid];
            #pragma unroll
            for (int off = 1; off < 16; off <<= 1) {
                int y = __shfl_up(w, off, 64);
                if (tid >= off) w += y;
            }
            wsum[tid] = w;
        }
        __syncthreads();
        int excl = running + (wid ? wsum[wid - 1] : 0) + (x - v);
        if (i < n) { rowptr[i] = excl; cursor[i] = excl; }
        running += wsum[15];
        __syncthreads();
    }
    if (tid == 0) rowptr[n] = running;
}

__global__ void scatter_kernel(const int* __restrict__ ei, int E, int N,
                               int* __restrict__ cursor,
                               int* __restrict__ esrc) {
    int i = blockIdx.x * blockDim.x + threadIdx.x;
    int Etot = E + N;
    if (i >= Etot) return;
    int src = (i < E) ? ei[i]     : (i - E);
    int dst = (i < E) ? ei[E + i] : (i - E);
    if (dst < 0 || dst >= N || src < 0 || src >= N) return;
    int pos = atomicAdd(&cursor[dst], 1);
    esrc[pos] = src;
}

// ---------------------------------------------------------------------------
// Dual GEMM, 32-row tile: xl = X@Wl + bl, xr = X@Wr + br.
// Same body as the proven 68-VGPR round-2 kernel (dual W streams keep the
// unroller sane — single-stream variant spilled to 256 VGPR), but half the
// tile so the grid is 1563 blocks (~6/CU) instead of 782 (~3/CU).
// ---------------------------------------------------------------------------
__global__ __launch_bounds__(256) void gemm_dual(
        const float* __restrict__ X,
        const float* __restrict__ Wl, const float* __restrict__ bl,
        const float* __restrict__ Wr, const float* __restrict__ br,
        float* __restrict__ xl, float* __restrict__ xr, int nrows) {
    __shared__ float xs[32][128];
    int tid = threadIdx.x;
    int i0  = blockIdx.x * 32;

    #pragma unroll
    for (int it = 0; it < 4; ++it) {
        int f   = it * 256 + tid;          // float4 index within 32x128 tile
        int row = f >> 5, c4 = f & 31;
        float4 v = make_float4(0.f, 0.f, 0.f, 0.f);
        if (i0 + row < nrows)
            v = *(const float4*)&X[(size_t)(i0 + row) * 128 + c4 * 4];
        *(float4*)&xs[row][c4 * 4] = v;
    }
    __syncthreads();

    int ty = tid >> 5, tx = tid & 31;      // ty: 4-row group, tx: col/4
    float accl[4][4] = {{0}}, accr[4][4] = {{0}};

    #pragma unroll 2
    for (int k = 0; k < 128; k += 4) {
        float4 a[4];
        #pragma unroll
        for (int r = 0; r < 4; ++r)
            a[r] = *(const float4*)&xs[ty * 4 + r][k];
        #pragma unroll
        for (int kk = 0; kk < 4; ++kk) {
            float4 wl = *(const float4*)&Wl[(size_t)(k + kk) * 128 + tx * 4];
            float4 wr = *(const float4*)&Wr[(size_t)(k + kk) * 128 + tx * 4];
            #pragma unroll
            for (int r = 0; r < 4; ++r) {
                float av = ((const float*)&a[r])[kk];
                accl[r][0] += av * wl.x; accl[r][1] += av * wl.y;
                accl[r][2] += av * wl.z; accl[r][3] += av * wl.w;
                accr[r][0] += av * wr.x; accr[r][1] += av * wr.y;
                accr[r][2] += av * wr.z; accr[r][3] += av * wr.w;
            }
        }
    }

    float4 vbl = *(const float4*)&bl[tx * 4];
    float4 vbr = *(const float4*)&br[tx * 4];
    #pragma unroll
    for (int r = 0; r < 4; ++r) {
        int row = i0 + ty * 4 + r;
        if (row >= nrows) continue;
        float4 ol = make_float4(accl[r][0] + vbl.x, accl[r][1] + vbl.y,
                                accl[r][2] + vbl.z, accl[r][3] + vbl.w);
        float4 orr = make_float4(accr[r][0] + vbr.x, accr[r][1] + vbr.y,
                                 accr[r][2] + vbr.z, accr[r][3] + vbr.w);
        *(float4*)&xl[(size_t)row * 128 + tx * 4] = ol;
        *(float4*)&xr[(size_t)row * 128 + tx * 4] = orr;
    }
}

// ---------------------------------------------------------------------------
// Fused GATv2 aggregation, 8 edges in flight per wave.
// ---------------------------------------------------------------------------
__device__ __forceinline__ float lrelu(float v) {
    return v > 0.f ? v : NEG * v;
}
__device__ __forceinline__ float dot4(float4 a, float4 x, float4 t) {
    return lrelu(a.x + x.x) * t.x + lrelu(a.y + x.y) * t.y
         + lrelu(a.z + x.z) * t.z + lrelu(a.w + x.w) * t.w;
}
__device__ __forceinline__ void fma4(float4& acc, float sc, float p, float4 a) {
    acc.x = acc.x * sc + p * a.x;  acc.y = acc.y * sc + p * a.y;
    acc.z = acc.z * sc + p * a.z;  acc.w = acc.w * sc + p * a.w;
}
__device__ __forceinline__ float4 shfl4(float4 v, int off) {
    float4 r;
    r.x = __shfl_xor(v.x, off, 64); r.y = __shfl_xor(v.y, off, 64);
    r.z = __shfl_xor(v.z, off, 64); r.w = __shfl_xor(v.w, off, 64);
    return r;
}
__device__ __forceinline__ void merge4(float4& acc, float sa, float4 o, float sb) {
    acc.x = acc.x * sa + o.x * sb;  acc.y = acc.y * sa + o.y * sb;
    acc.z = acc.z * sa + o.z * sb;  acc.w = acc.w * sa + o.w * sb;
}

__global__ __launch_bounds__(256) void gat_aggregate(
        const float* __restrict__ xl, const float* __restrict__ xr,
        const int* __restrict__ rowptr, const int* __restrict__ esrc,
        const float* __restrict__ att, const float* __restrict__ bias,
        float* __restrict__ hout, int n, int do_relu) {
    int node = (int)((blockIdx.x * blockDim.x + threadIdx.x) >> 6);
    int lane = threadIdx.x & 63;
    if (node >= n) return;
    int g  = lane >> 3;      // 8 groups of 8 lanes
    int gl = lane & 7;
    int c0 = gl * 8;

    const float* xrp = &xr[(size_t)node * 128];
    float4 xr0a = *(const float4*)&xrp[c0],      xr0b = *(const float4*)&xrp[c0 + 4];
    float4 xr1a = *(const float4*)&xrp[64 + c0], xr1b = *(const float4*)&xrp[64 + c0 + 4];
    float4 at0a = *(const float4*)&att[c0],      at0b = *(const float4*)&att[c0 + 4];
    float4 at1a = *(const float4*)&att[64 + c0], at1b = *(const float4*)&att[64 + c0 + 4];

    float m0 = -1e30f, m1 = -1e30f, s0 = 0.f, s1 = 0.f;
    float4 acc0a = make_float4(0,0,0,0), acc0b = make_float4(0,0,0,0);
    float4 acc1a = make_float4(0,0,0,0), acc1b = make_float4(0,0,0,0);

    int pbeg = rowptr[node], pend = rowptr[node + 1];
    for (int p = pbeg + g; p < pend; p += 8) {
        int s = esrc[p];
        const float* xlp = &xl[(size_t)s * 128];
        float4 a0a = *(const float4*)&xlp[c0],      a0b = *(const float4*)&xlp[c0 + 4];
        float4 a1a = *(const float4*)&xlp[64 + c0], a1b = *(const float4*)&xlp[64 + c0 + 4];

        float t0 = dot4(a0a, xr0a, at0a) + dot4(a0b, xr0b, at0b);
        float t1 = dot4(a1a, xr1a, at1a) + dot4(a1b, xr1b, at1b);
        #pragma unroll
        for (int off = 1; off < 8; off <<= 1) {
            t0 += __shfl_xor(t0, off, 64);
            t1 += __shfl_xor(t1, off, 64);
        }

        float nm0 = fmaxf(m0, t0), nm1 = fmaxf(m1, t1);
        float sc0 = __expf(m0 - nm0), sc1 = __expf(m1 - nm1);
        float p0  = __expf(t0 - nm0), p1  = __expf(t1 - nm1);
        s0 = s0 * sc0 + p0;  s1 = s1 * sc1 + p1;
        fma4(acc0a, sc0, p0, a0a);  fma4(acc0b, sc0, p0, a0b);
        fma4(acc1a, sc1, p1, a1a);  fma4(acc1b, sc1, p1, a1b);
        m0 = nm0; m1 = nm1;
    }

    // flash-merge the 8 group states (xor 8, 16, 32)
    #pragma unroll
    for (int off = 8; off <= 32; off <<= 1) {
        float om0 = __shfl_xor(m0, off, 64), om1 = __shfl_xor(m1, off, 64);
        float os0 = __shfl_xor(s0, off, 64), os1 = __shfl_xor(s1, off, 64);
        float4 oa0a = shfl4(acc0a, off), oa0b = shfl4(acc0b, off);
        float4 oa1a = shfl4(acc1a, off), oa1b = shfl4(acc1b, off);

        float nm0 = fmaxf(m0, om0), nm1 = fmaxf(m1, om1);
        float sa0 = __expf(m0 - nm0),  sb0 = __expf(om0 - nm0);
        float sa1 = __expf(m1 - nm1),  sb1 = __expf(om1 - nm1);
        s0 = s0 * sa0 + os0 * sb0;  s1 = s1 * sa1 + os1 * sb1;
        merge4(acc0a, sa0, oa0a, sb0);  merge4(acc0b, sa0, oa0b, sb0);
        merge4(acc1a, sa1, oa1a, sb1);  merge4(acc1b, sa1, oa1b, sb1);
        m0 = nm0; m1 = nm1;
    }

    if (g == 0) {
        float inv = 1.f / s0;
        float4 vba = *(const float4*)&bias[c0], vbb = *(const float4*)&bias[c0 + 4];
        float4 oa = make_float4(acc0a.x * inv + vba.x, acc0a.y * inv + vba.y,
                                acc0a.z * inv + vba.z, acc0a.w * inv + vba.w);
        float4 ob = make_float4(acc0b.x * inv + vbb.x, acc0b.y * inv + vbb.y,
                                acc0b.z * inv + vbb.z, acc0b.w * inv + vbb.w);
        if (do_relu) {
            oa.x = fmaxf(oa.x, 0.f); oa.y = fmaxf(oa.y, 0.f);
            oa.z = fmaxf(oa.z, 0.f); oa.w = fmaxf(oa.w, 0.f);
            ob.x = fmaxf(ob.x, 0.f); ob.y = fmaxf(ob.y, 0.f);
            ob.z = fmaxf(ob.z, 0.f); ob.w = fmaxf(ob.w, 0.f);
        }
        *(float4*)&hout[(size_t)node * 128 + c0]     = oa;
        *(float4*)&hout[(size_t)node * 128 + c0 + 4] = ob;
    } else if (g == 1) {
        float inv = 1.f / s1;
        float4 vba = *(const float4*)&bias[64 + c0], vbb = *(const float4*)&bias[64 + c0 + 4];
        float4 oa = make_float4(acc1a.x * inv + vba.x, acc1a.y * inv + vba.y,
                                acc1a.z * inv + vba.z, acc1a.w * inv + vba.w);
        float4 ob = make_float4(acc1b.x * inv + vbb.x, acc1b.y * inv + vbb.y,
                                acc1b.z * inv + vbb.z, acc1b.w * inv + vbb.w);
        if (do_relu) {
            oa.x = fmaxf(oa.x, 0.f); oa.y = fmaxf(oa.y, 0.f);
            oa.z = fmaxf(oa.z, 0.f); oa.w = fmaxf(oa.w, 0.f);
            ob.x = fmaxf(ob.x, 0.f); ob.y = fmaxf(ob.y, 0.f);
            ob.z = fmaxf(ob.z, 0.f); ob.w = fmaxf(ob.w, 0.f);
        }
        *(float4*)&hout[(size_t)node * 128 + 64 + c0]     = oa;
        *(float4*)&hout[(size_t)node * 128 + 64 + c0 + 4] = ob;
    }
}

// ---------------------------------------------------------------------------
// Output linear: out = h @ Wout + bout.  Wout:[128,4] row-major.
// ---------------------------------------------------------------------------
__global__ __launch_bounds__(256) void out_linear(
        const float* __restrict__ h, const float* __restrict__ Wout,
        const float* __restrict__ bout, float* __restrict__ out, int n) {
    int node = (int)((blockIdx.x * blockDim.x + threadIdx.x) >> 6);
    int lane = threadIdx.x & 63;
    if (node >= n) return;
    float h0 = h[(size_t)node * 128 + lane];
    float h1 = h[(size_t)node * 128 + 64 + lane];
    float4 w0 = *(const float4*)&Wout[lane * 4];
    float4 w1 = *(const float4*)&Wout[(64 + lane) * 4];
    float p0 = h0 * w0.x + h1 * w1.x;
    float p1 = h0 * w0.y + h1 * w1.y;
    float p2 = h0 * w0.z + h1 * w1.z;
    float p3 = h0 * w0.w + h1 * w1.w;
    #pragma unroll
    for (int off = 32; off > 0; off >>= 1) {
        p0 += __shfl_xor(p0, off, 64);
        p1 += __shfl_xor(p1, off, 64);
        p2 += __shfl_xor(p2, off, 64);
        p3 += __shfl_xor(p3, off, 64);
    }
    if (lane == 0) {
        float4 o = make_float4(p0 + bout[0], p1 + bout[1],
                               p2 + bout[2], p3 + bout[3]);
        *(float4*)&out[(size_t)node * 4] = o;
    }
}

// ---------------------------------------------------------------------------
extern "C" void kernel_launch(void* const* d_in, const int* in_sizes, int n_in,
                              void* d_out, int out_size, void* d_ws,
                              size_t ws_size, hipStream_t stream) {
    const float* x    = (const float*)d_in[0];
    const int*   ei   = (const int*)  d_in[1];
    const float* W1l  = (const float*)d_in[2];
    const float* b1l  = (const float*)d_in[3];
    const float* W1r  = (const float*)d_in[4];
    const float* b1r  = (const float*)d_in[5];
    const float* att1 = (const float*)d_in[6];
    const float* bias1= (const float*)d_in[7];
    const float* W2l  = (const float*)d_in[8];
    const float* b2l  = (const float*)d_in[9];
    const float* W2r  = (const float*)d_in[10];
    const float* b2r  = (const float*)d_in[11];
    const float* att2 = (const float*)d_in[12];
    const float* bias2= (const float*)d_in[13];
    const float* W3l  = (const float*)d_in[14];
    const float* b3l  = (const float*)d_in[15];
    const float* W3r  = (const float*)d_in[16];
    const float* b3r  = (const float*)d_in[17];
    const float* att3 = (const float*)d_in[18];
    const float* bias3= (const float*)d_in[19];
    const float* Wout = (const float*)d_in[20];
    const float* bout = (const float*)d_in[21];

    int N    = in_sizes[0] / DIN;
    int E    = in_sizes[1] / 2;
    int Etot = E + N;

    float* h      = (float*)d_ws;
    float* xl     = h  + (size_t)N * HC;
    float* xr     = xl + (size_t)N * HC;
    int*   esrc   = (int*)(xr + (size_t)N * HC);
    int*   rowptr = esrc + Etot;
    int*   cursor = rowptr + (N + 1);
    int*   counts = cursor + N;

    hipMemsetAsync(counts, 0, (size_t)N * sizeof(int), stream);
    hist_kernel<<<(Etot + 255) / 256, 256, 0, stream>>>(ei, E, N, counts);
    scan_kernel<<<1, 1024, 0, stream>>>(counts, rowptr, cursor, N);
    scatter_kernel<<<(Etot + 255) / 256, 256, 0, stream>>>(ei, E, N, cursor, esrc);

    int gemm_grid = (N + 31) / 32;
    int agg_grid  = (N + 3) / 4;

    gemm_dual<<<gemm_grid, 256, 0, stream>>>(x, W1l, b1l, W1r, b1r, xl, xr, N);
    gat_aggregate<<<agg_grid, 256, 0, stream>>>(xl, xr, rowptr, esrc, att1, bias1, h, N, 1);
    gemm_dual<<<gemm_grid, 256, 0, stream>>>(h, W2l, b2l, W2r, b2r, xl, xr, N);
    gat_aggregate<<<agg_grid, 256, 0, stream>>>(xl, xr, rowptr, esrc, att2, bias2, h, N, 1);
    gemm_dual<<<gemm_grid, 256, 0, stream>>>(h, W3l, b3l, W3r, b3r, xl, xr, N);
    gat_aggregate<<<agg_grid, 256, 0, stream>>>(xl, xr, rowptr, esrc, att3, bias3, h, N, 1);
    out_linear<<<(N + 3) / 4, 256, 0, stream>>>(h, Wout, bout, (float*)d_out, N);
}

// Round 5
// 455.396 us; speedup vs baseline: 8.4682x; 1.4041x over previous
//
#include <hip/hip_runtime.h>
#include <math.h>

#define DIN  128
#define HC   128
#define NEG  0.2f

typedef __attribute__((ext_vector_type(8))) short bf16x8;
typedef __attribute__((ext_vector_type(4))) float f32x4;

__device__ __forceinline__ unsigned short f2bf_rne(float x) {
    unsigned u = __float_as_uint(x);
    unsigned r = u + 0x7FFFu + ((u >> 16) & 1u);
    return (unsigned short)(r >> 16);
}
__device__ __forceinline__ float bf2f(unsigned short h) {
    return __uint_as_float(((unsigned)h) << 16);
}

// ---------------------------------------------------------------------------
// CSR build
// ---------------------------------------------------------------------------
__global__ void hist_kernel(const int* __restrict__ ei, int E, int N,
                            int* __restrict__ counts) {
    int i = blockIdx.x * blockDim.x + threadIdx.x;
    int Etot = E + N;
    if (i >= Etot) return;
    int dst = (i < E) ? ei[E + i] : (i - E);
    if (dst < 0 || dst >= N) return;
    atomicAdd(&counts[dst], 1);
}

__global__ void scan_kernel(const int* __restrict__ counts,
                            int* __restrict__ rowptr,
                            int* __restrict__ cursor, int n) {
    __shared__ int wsum[16];
    int tid  = threadIdx.x;          // 1024 threads
    int lane = tid & 63, wid = tid >> 6;
    int running = 0;
    for (int base = 0; base < n; base += 1024) {
        int i = base + tid;
        int v = (i < n) ? counts[i] : 0;
        int x = v;
        #pragma unroll
        for (int off = 1; off < 64; off <<= 1) {
            int y = __shfl_up(x, off, 64);
            if (lane >= off) x += y;
        }
        if (lane == 63) wsum[wid] = x;
        __syncthreads();
        if (tid < 16) {
            int w = wsum[tid];
            #pragma unroll
            for (int off = 1; off < 16; off <<= 1) {
                int y = __shfl_up(w, off, 64);
                if (tid >= off) w += y;
            }
            wsum[tid] = w;
        }
        __syncthreads();
        int excl = running + (wid ? wsum[wid - 1] : 0) + (x - v);
        if (i < n) { rowptr[i] = excl; cursor[i] = excl; }
        running += wsum[15];
        __syncthreads();
    }
    if (tid == 0) rowptr[n] = running;
}

__global__ void scatter_kernel(const int* __restrict__ ei, int E, int N,
                               int* __restrict__ cursor,
                               int* __restrict__ esrc) {
    int i = blockIdx.x * blockDim.x + threadIdx.x;
    int Etot = E + N;
    if (i >= Etot) return;
    int src = (i < E) ? ei[i]     : (i - E);
    int dst = (i < E) ? ei[E + i] : (i - E);
    if (dst < 0 || dst >= N || src < 0 || src >= N) return;
    int pos = atomicAdd(&cursor[dst], 1);
    esrc[pos] = src;
}

// ---------------------------------------------------------------------------
// W prep: split each 128x128 W into bf16 hi/lo, packed in MFMA B-fragment
// order: slot (kb,nf,lane,j) = W[kb*32 + (lane>>4)*8 + j][nf*16 + (lane&15)].
// Correctness relies only on A and B sharing the same (lane,j)->k convention
// (k-permutation invariance of a full-K MFMA dot product) and n = lane&15.
// ---------------------------------------------------------------------------
__global__ __launch_bounds__(256) void prep_w(
        const float* __restrict__ W1l, const float* __restrict__ W1r,
        const float* __restrict__ W2l, const float* __restrict__ W2r,
        const float* __restrict__ W3l, const float* __restrict__ W3r,
        unsigned short* __restrict__ hi, unsigned short* __restrict__ lo) {
    int m = blockIdx.y;
    const float* W = (m == 0) ? W1l : (m == 1) ? W1r : (m == 2) ? W2l
                   : (m == 3) ? W2r : (m == 4) ? W3l : W3r;
    int t = blockIdx.x * 256 + threadIdx.x;    // 0..2047 (grid.x = 8)
    int kb = t >> 9, nf = (t >> 6) & 7, l = t & 63;
    int col = nf * 16 + (l & 15);
    int k0  = kb * 32 + (l >> 4) * 8;
    size_t ob = ((size_t)m * 2048 + t) * 8;
    #pragma unroll
    for (int j = 0; j < 8; ++j) {
        float v = W[(size_t)(k0 + j) * 128 + col];
        unsigned short h = f2bf_rne(v);
        hi[ob + j] = h;
        lo[ob + j] = f2bf_rne(v - bf2f(h));
    }
}

// ---------------------------------------------------------------------------
// MFMA GEMM (split-bf16, 3 terms): Out = X@W + b, X:[n,128] fp32, W packed.
// Grid (ceil(n/64), 2): y selects (l) or (r) stream. Block = 4 waves; wave w
// computes rows [bx*64 + w*16, +16) x all 128 cols. acc = 8 x f32x4.
// ---------------------------------------------------------------------------
__global__ __launch_bounds__(256) void gemm_mfma(
        const float* __restrict__ X,
        const unsigned short* __restrict__ Whi,
        const unsigned short* __restrict__ Wlo, int matbase,
        const float* __restrict__ bl, const float* __restrict__ br,
        float* __restrict__ xl, float* __restrict__ xr, int nrows) {
    const float* bias = blockIdx.y ? br : bl;
    float*       Out  = blockIdx.y ? xr : xl;
    const unsigned short* hp = Whi + ((size_t)(matbase + blockIdx.y) * 16384);
    const unsigned short* lp = Wlo + ((size_t)(matbase + blockIdx.y) * 16384);

    int w   = threadIdx.x >> 6;
    int l   = threadIdx.x & 63;
    int m15 = l & 15, g = l >> 4;
    int rowbase = blockIdx.x * 64 + w * 16;

    f32x4 acc[8];
    #pragma unroll
    for (int nf = 0; nf < 8; ++nf) acc[nf] = (f32x4){0.f, 0.f, 0.f, 0.f};

    #pragma unroll
    for (int kb = 0; kb < 4; ++kb) {
        // A fragment: row = rowbase + m15, k = kb*32 + g*8 + j
        int arow = rowbase + m15;
        float4 x0 = make_float4(0.f, 0.f, 0.f, 0.f), x1 = x0;
        if (arow < nrows) {
            const float* xp = &X[(size_t)arow * 128 + kb * 32 + g * 8];
            x0 = *(const float4*)xp;
            x1 = *(const float4*)(xp + 4);
        }
        float xv[8] = {x0.x, x0.y, x0.z, x0.w, x1.x, x1.y, x1.z, x1.w};
        bf16x8 ahi, alo;
        #pragma unroll
        for (int j = 0; j < 8; ++j) {
            unsigned short h = f2bf_rne(xv[j]);
            ahi[j] = (short)h;
            alo[j] = (short)f2bf_rne(xv[j] - bf2f(h));
        }
        #pragma unroll
        for (int nf = 0; nf < 8; ++nf) {
            size_t off = (((size_t)kb * 8 + nf) * 64 + l) * 8;
            bf16x8 bhi = *(const bf16x8*)&hp[off];
            bf16x8 blo = *(const bf16x8*)&lp[off];
            acc[nf] = __builtin_amdgcn_mfma_f32_16x16x32_bf16(ahi, bhi, acc[nf], 0, 0, 0);
            acc[nf] = __builtin_amdgcn_mfma_f32_16x16x32_bf16(ahi, blo, acc[nf], 0, 0, 0);
            acc[nf] = __builtin_amdgcn_mfma_f32_16x16x32_bf16(alo, bhi, acc[nf], 0, 0, 0);
        }
    }

    // C/D layout: col = lane&15, row = (lane>>4)*4 + reg  [m89-verified]
    #pragma unroll
    for (int nf = 0; nf < 8; ++nf) {
        int col = nf * 16 + m15;
        float b = bias[col];
        #pragma unroll
        for (int r = 0; r < 4; ++r) {
            int row = rowbase + g * 4 + r;
            if (row < nrows)
                Out[(size_t)row * 128 + col] = acc[nf][r] + b;
        }
    }
}

// ---------------------------------------------------------------------------
// Fused GATv2 aggregation, 4 edges in flight per wave (round-2 proven 68us).
// Wave = 1 node. Lanes: 4 groups x 16; group g owns edges pbeg+g, +4...
// ---------------------------------------------------------------------------
__device__ __forceinline__ float lrelu(float v) {
    return v > 0.f ? v : NEG * v;
}

__global__ __launch_bounds__(256) void gat_aggregate(
        const float* __restrict__ xl, const float* __restrict__ xr,
        const int* __restrict__ rowptr, const int* __restrict__ esrc,
        const float* __restrict__ att, const float* __restrict__ bias,
        float* __restrict__ hout, int n, int do_relu) {
    int node = (int)((blockIdx.x * blockDim.x + threadIdx.x) >> 6);
    int lane = threadIdx.x & 63;
    if (node >= n) return;
    int g  = lane >> 4;
    int gl = lane & 15;
    int c0 = gl * 4;

    const float* xrp = &xr[(size_t)node * 128];
    float4 xr0 = *(const float4*)&xrp[c0];
    float4 xr1 = *(const float4*)&xrp[64 + c0];
    float4 at0 = *(const float4*)&att[c0];
    float4 at1 = *(const float4*)&att[64 + c0];

    float m0 = -1e30f, m1 = -1e30f, s0 = 0.f, s1 = 0.f;
    float4 acc0 = make_float4(0.f, 0.f, 0.f, 0.f);
    float4 acc1 = make_float4(0.f, 0.f, 0.f, 0.f);

    int pbeg = rowptr[node], pend = rowptr[node + 1];
    for (int p = pbeg + g; p < pend; p += 4) {
        int s = esrc[p];
        const float* xlp = &xl[(size_t)s * 128];
        float4 a0 = *(const float4*)&xlp[c0];
        float4 a1 = *(const float4*)&xlp[64 + c0];

        float t0 = lrelu(a0.x + xr0.x) * at0.x + lrelu(a0.y + xr0.y) * at0.y
                 + lrelu(a0.z + xr0.z) * at0.z + lrelu(a0.w + xr0.w) * at0.w;
        float t1 = lrelu(a1.x + xr1.x) * at1.x + lrelu(a1.y + xr1.y) * at1.y
                 + lrelu(a1.z + xr1.z) * at1.z + lrelu(a1.w + xr1.w) * at1.w;
        #pragma unroll
        for (int off = 1; off < 16; off <<= 1) {
            t0 += __shfl_xor(t0, off, 64);
            t1 += __shfl_xor(t1, off, 64);
        }

        float nm0 = fmaxf(m0, t0), nm1 = fmaxf(m1, t1);
        float sc0 = __expf(m0 - nm0), sc1 = __expf(m1 - nm1);
        float p0  = __expf(t0 - nm0), p1  = __expf(t1 - nm1);
        s0 = s0 * sc0 + p0;  s1 = s1 * sc1 + p1;
        acc0.x = acc0.x * sc0 + p0 * a0.x;  acc0.y = acc0.y * sc0 + p0 * a0.y;
        acc0.z = acc0.z * sc0 + p0 * a0.z;  acc0.w = acc0.w * sc0 + p0 * a0.w;
        acc1.x = acc1.x * sc1 + p1 * a1.x;  acc1.y = acc1.y * sc1 + p1 * a1.y;
        acc1.z = acc1.z * sc1 + p1 * a1.z;  acc1.w = acc1.w * sc1 + p1 * a1.w;
        m0 = nm0; m1 = nm1;
    }

    // flash-merge the 4 group states (xor 16 then 32)
    #pragma unroll
    for (int off = 16; off <= 32; off <<= 1) {
        float om0 = __shfl_xor(m0, off, 64), om1 = __shfl_xor(m1, off, 64);
        float os0 = __shfl_xor(s0, off, 64), os1 = __shfl_xor(s1, off, 64);
        float4 oa0, oa1;
        oa0.x = __shfl_xor(acc0.x, off, 64); oa0.y = __shfl_xor(acc0.y, off, 64);
        oa0.z = __shfl_xor(acc0.z, off, 64); oa0.w = __shfl_xor(acc0.w, off, 64);
        oa1.x = __shfl_xor(acc1.x, off, 64); oa1.y = __shfl_xor(acc1.y, off, 64);
        oa1.z = __shfl_xor(acc1.z, off, 64); oa1.w = __shfl_xor(acc1.w, off, 64);

        float nm0 = fmaxf(m0, om0), nm1 = fmaxf(m1, om1);
        float sa0 = __expf(m0 - nm0),  sb0 = __expf(om0 - nm0);
        float sa1 = __expf(m1 - nm1),  sb1 = __expf(om1 - nm1);
        s0 = s0 * sa0 + os0 * sb0;  s1 = s1 * sa1 + os1 * sb1;
        acc0.x = acc0.x * sa0 + oa0.x * sb0;  acc0.y = acc0.y * sa0 + oa0.y * sb0;
        acc0.z = acc0.z * sa0 + oa0.z * sb0;  acc0.w = acc0.w * sa0 + oa0.w * sb0;
        acc1.x = acc1.x * sa1 + oa1.x * sb1;  acc1.y = acc1.y * sa1 + oa1.y * sb1;
        acc1.z = acc1.z * sa1 + oa1.z * sb1;  acc1.w = acc1.w * sa1 + oa1.w * sb1;
        m0 = nm0; m1 = nm1;
    }

    float inv0 = 1.f / s0, inv1 = 1.f / s1;
    if (g == 0) {
        float4 vb = *(const float4*)&bias[c0];
        float4 o = make_float4(acc0.x * inv0 + vb.x, acc0.y * inv0 + vb.y,
                               acc0.z * inv0 + vb.z, acc0.w * inv0 + vb.w);
        if (do_relu) {
            o.x = fmaxf(o.x, 0.f); o.y = fmaxf(o.y, 0.f);
            o.z = fmaxf(o.z, 0.f); o.w = fmaxf(o.w, 0.f);
        }
        *(float4*)&hout[(size_t)node * 128 + c0] = o;
    } else if (g == 1) {
        float4 vb = *(const float4*)&bias[64 + c0];
        float4 o = make_float4(acc1.x * inv1 + vb.x, acc1.y * inv1 + vb.y,
                               acc1.z * inv1 + vb.z, acc1.w * inv1 + vb.w);
        if (do_relu) {
            o.x = fmaxf(o.x, 0.f); o.y = fmaxf(o.y, 0.f);
            o.z = fmaxf(o.z, 0.f); o.w = fmaxf(o.w, 0.f);
        }
        *(float4*)&hout[(size_t)node * 128 + 64 + c0] = o;
    }
}

// ---------------------------------------------------------------------------
// Output linear: out = h @ Wout + bout.  Wout:[128,4] row-major.
// ---------------------------------------------------------------------------
__global__ __launch_bounds__(256) void out_linear(
        const float* __restrict__ h, const float* __restrict__ Wout,
        const float* __restrict__ bout, float* __restrict__ out, int n) {
    int node = (int)((blockIdx.x * blockDim.x + threadIdx.x) >> 6);
    int lane = threadIdx.x & 63;
    if (node >= n) return;
    float h0 = h[(size_t)node * 128 + lane];
    float h1 = h[(size_t)node * 128 + 64 + lane];
    float4 w0 = *(const float4*)&Wout[lane * 4];
    float4 w1 = *(const float4*)&Wout[(64 + lane) * 4];
    float p0 = h0 * w0.x + h1 * w1.x;
    float p1 = h0 * w0.y + h1 * w1.y;
    float p2 = h0 * w0.z + h1 * w1.z;
    float p3 = h0 * w0.w + h1 * w1.w;
    #pragma unroll
    for (int off = 32; off > 0; off >>= 1) {
        p0 += __shfl_xor(p0, off, 64);
        p1 += __shfl_xor(p1, off, 64);
        p2 += __shfl_xor(p2, off, 64);
        p3 += __shfl_xor(p3, off, 64);
    }
    if (lane == 0) {
        float4 o = make_float4(p0 + bout[0], p1 + bout[1],
                               p2 + bout[2], p3 + bout[3]);
        *(float4*)&out[(size_t)node * 4] = o;
    }
}

// ---------------------------------------------------------------------------
extern "C" void kernel_launch(void* const* d_in, const int* in_sizes, int n_in,
                              void* d_out, int out_size, void* d_ws,
                              size_t ws_size, hipStream_t stream) {
    const float* x    = (const float*)d_in[0];
    const int*   ei   = (const int*)  d_in[1];
    const float* W1l  = (const float*)d_in[2];
    const float* b1l  = (const float*)d_in[3];
    const float* W1r  = (const float*)d_in[4];
    const float* b1r  = (const float*)d_in[5];
    const float* att1 = (const float*)d_in[6];
    const float* bias1= (const float*)d_in[7];
    const float* W2l  = (const float*)d_in[8];
    const float* b2l  = (const float*)d_in[9];
    const float* W2r  = (const float*)d_in[10];
    const float* b2r  = (const float*)d_in[11];
    const float* W3l  = (const float*)d_in[12];
    const float* b3l  = (const float*)d_in[13];
    const float* W3r  = (const float*)d_in[14];
    const float* b3r  = (const float*)d_in[15];
    const float* att3 = (const float*)d_in[18];
    const float* bias3= (const float*)d_in[19];
    const float* Wout = (const float*)d_in[20];
    const float* bout = (const float*)d_in[21];
    // NOTE: careful index audit against setup_inputs order:
    //  0:x 1:edge_index 2:W1l 3:b1l 4:W1r 5:b1r 6:att1 7:bias1
    //  8:W2l 9:b2l 10:W2r 11:b2r 12:att2 13:bias2
    // 14:W3l 15:b3l 16:W3r 17:b3r 18:att3 19:bias3 20:Wout 21:bout
    const float* att2 = (const float*)d_in[12];
    const float* bias2= (const float*)d_in[13];
    // re-bind layer-2/3 weights per the audited order above:
    const float* W2l_ = (const float*)d_in[8];
    const float* b2l_ = (const float*)d_in[9];
    const float* W2r_ = (const float*)d_in[10];
    const float* b2r_ = (const float*)d_in[11];
    const float* W3l_ = (const float*)d_in[14];
    const float* b3l_ = (const float*)d_in[15];
    const float* W3r_ = (const float*)d_in[16];
    const float* b3r_ = (const float*)d_in[17];

    int N    = in_sizes[0] / DIN;
    int E    = in_sizes[1] / 2;
    int Etot = E + N;

    float* h      = (float*)d_ws;
    float* xl     = h  + (size_t)N * HC;
    float* xr     = xl + (size_t)N * HC;
    unsigned short* whi = (unsigned short*)(xr + (size_t)N * HC);
    unsigned short* wlo = whi + 6 * 16384;
    int*   esrc   = (int*)(wlo + 6 * 16384);
    int*   rowptr = esrc + Etot;
    int*   cursor = rowptr + (N + 1);
    int*   counts = cursor + N;

    hipMemsetAsync(counts, 0, (size_t)N * sizeof(int), stream);
    hist_kernel<<<(Etot + 255) / 256, 256, 0, stream>>>(ei, E, N, counts);
    scan_kernel<<<1, 1024, 0, stream>>>(counts, rowptr, cursor, N);
    scatter_kernel<<<(Etot + 255) / 256, 256, 0, stream>>>(ei, E, N, cursor, esrc);
    prep_w<<<dim3(8, 6), 256, 0, stream>>>(W1l, W1r, W2l_, W2r_, W3l_, W3r_, whi, wlo);

    dim3 gemm_grid((N + 63) / 64, 2);
    int  agg_grid = (N + 3) / 4;

    gemm_mfma<<<gemm_grid, 256, 0, stream>>>(x, whi, wlo, 0, b1l, b1r, xl, xr, N);
    gat_aggregate<<<agg_grid, 256, 0, stream>>>(xl, xr, rowptr, esrc, att1, bias1, h, N, 1);
    gemm_mfma<<<gemm_grid, 256, 0, stream>>>(h, whi, wlo, 2, b2l_, b2r_, xl, xr, N);
    gat_aggregate<<<agg_grid, 256, 0, stream>>>(xl, xr, rowptr, esrc, att2, bias2, h, N, 1);
    gemm_mfma<<<gemm_grid, 256, 0, stream>>>(h, whi, wlo, 4, b3l_, b3r_, xl, xr, N);
    gat_aggregate<<<agg_grid, 256, 0, stream>>>(xl, xr, rowptr, esrc, att3, bias3, h, N, 1);
    out_linear<<<(N + 3) / 4, 256, 0, stream>>>(h, Wout, bout, (float*)d_out, N);
}

// Round 6
// 421.245 us; speedup vs baseline: 9.1547x; 1.0811x over previous
//
#include <hip/hip_runtime.h>
#include <math.h>

#define DIN  128
#define HC   128
#define NEG  0.2f

typedef __attribute__((ext_vector_type(8))) short bf16x8;
typedef __attribute__((ext_vector_type(4))) float f32x4;

__device__ __forceinline__ unsigned short f2bf_rne(float x) {
    unsigned u = __float_as_uint(x);
    unsigned r = u + 0x7FFFu + ((u >> 16) & 1u);
    return (unsigned short)(r >> 16);
}
__device__ __forceinline__ float bf2f(unsigned short h) {
    return __uint_as_float(((unsigned)h) << 16);
}

// ---------------------------------------------------------------------------
// CSR build
// ---------------------------------------------------------------------------
__global__ void hist_kernel(const int* __restrict__ ei, int E, int N,
                            int* __restrict__ counts) {
    int i = blockIdx.x * blockDim.x + threadIdx.x;
    int Etot = E + N;
    if (i >= Etot) return;
    int dst = (i < E) ? ei[E + i] : (i - E);
    if (dst < 0 || dst >= N) return;
    atomicAdd(&counts[dst], 1);
}

// single-block scan, 4 elems/thread (int4) -> 13 outer iterations at N=50K
__global__ void scan_kernel(const int* __restrict__ counts,
                            int* __restrict__ rowptr,
                            int* __restrict__ cursor, int n) {
    __shared__ int wsum[16];
    int tid  = threadIdx.x;          // 1024 threads
    int lane = tid & 63, wid = tid >> 6;
    int running = 0;
    for (int base = 0; base < n; base += 4096) {
        int i = base + tid * 4;
        int4 v = make_int4(0, 0, 0, 0);
        if (i < n) v = *(const int4*)&counts[i];   // n % 4 == 0
        int ssum = v.x + v.y + v.z + v.w;
        int x = ssum;
        #pragma unroll
        for (int off = 1; off < 64; off <<= 1) {
            int y = __shfl_up(x, off, 64);
            if (lane >= off) x += y;
        }
        if (lane == 63) wsum[wid] = x;
        __syncthreads();
        if (tid < 16) {
            int w = wsum[tid];
            #pragma unroll
            for (int off = 1; off < 16; off <<= 1) {
                int y = __shfl_up(w, off, 64);
                if (tid >= off) w += y;
            }
            wsum[tid] = w;
        }
        __syncthreads();
        int excl = running + (wid ? wsum[wid - 1] : 0) + (x - ssum);
        if (i < n) {
            int4 r;
            r.x = excl;
            r.y = r.x + v.x;
            r.z = r.y + v.y;
            r.w = r.z + v.z;
            *(int4*)&rowptr[i] = r;
            *(int4*)&cursor[i] = r;
        }
        running += wsum[15];
        __syncthreads();
    }
    if (tid == 0) rowptr[n] = running;
}

__global__ void scatter_kernel(const int* __restrict__ ei, int E, int N,
                               int* __restrict__ cursor,
                               int* __restrict__ esrc) {
    int i = blockIdx.x * blockDim.x + threadIdx.x;
    int Etot = E + N;
    if (i >= Etot) return;
    int src = (i < E) ? ei[i]     : (i - E);
    int dst = (i < E) ? ei[E + i] : (i - E);
    if (dst < 0 || dst >= N || src < 0 || src >= N) return;
    int pos = atomicAdd(&cursor[dst], 1);
    esrc[pos] = src;
}

// ---------------------------------------------------------------------------
// W prep: split each 128x128 W into bf16 hi/lo, packed in MFMA B-fragment
// order: slot (kb,nf,lane,j) = W[kb*32 + (lane>>4)*8 + j][nf*16 + (lane&15)].
// ---------------------------------------------------------------------------
__global__ __launch_bounds__(256) void prep_w(
        const float* __restrict__ W1l, const float* __restrict__ W1r,
        const float* __restrict__ W2l, const float* __restrict__ W2r,
        const float* __restrict__ W3l, const float* __restrict__ W3r,
        unsigned short* __restrict__ hi, unsigned short* __restrict__ lo) {
    int m = blockIdx.y;
    const float* W = (m == 0) ? W1l : (m == 1) ? W1r : (m == 2) ? W2l
                   : (m == 3) ? W2r : (m == 4) ? W3l : W3r;
    int t = blockIdx.x * 256 + threadIdx.x;    // 0..2047 (grid.x = 8)
    int kb = t >> 9, nf = (t >> 6) & 7, l = t & 63;
    int col = nf * 16 + (l & 15);
    int k0  = kb * 32 + (l >> 4) * 8;
    size_t ob = ((size_t)m * 2048 + t) * 8;
    #pragma unroll
    for (int j = 0; j < 8; ++j) {
        float v = W[(size_t)(k0 + j) * 128 + col];
        unsigned short h = f2bf_rne(v);
        hi[ob + j] = h;
        lo[ob + j] = f2bf_rne(v - bf2f(h));
    }
}

// ---------------------------------------------------------------------------
// MFMA GEMM (split-bf16, 3 terms): Out = X@W + b, X:[n,128] fp32, W packed.
// ---------------------------------------------------------------------------
__global__ __launch_bounds__(256) void gemm_mfma(
        const float* __restrict__ X,
        const unsigned short* __restrict__ Whi,
        const unsigned short* __restrict__ Wlo, int matbase,
        const float* __restrict__ bl, const float* __restrict__ br,
        float* __restrict__ xl, float* __restrict__ xr, int nrows) {
    const float* bias = blockIdx.y ? br : bl;
    float*       Out  = blockIdx.y ? xr : xl;
    const unsigned short* hp = Whi + ((size_t)(matbase + blockIdx.y) * 16384);
    const unsigned short* lp = Wlo + ((size_t)(matbase + blockIdx.y) * 16384);

    int w   = threadIdx.x >> 6;
    int l   = threadIdx.x & 63;
    int m15 = l & 15, g = l >> 4;
    int rowbase = blockIdx.x * 64 + w * 16;

    f32x4 acc[8];
    #pragma unroll
    for (int nf = 0; nf < 8; ++nf) acc[nf] = (f32x4){0.f, 0.f, 0.f, 0.f};

    #pragma unroll
    for (int kb = 0; kb < 4; ++kb) {
        int arow = rowbase + m15;
        float4 x0 = make_float4(0.f, 0.f, 0.f, 0.f), x1 = x0;
        if (arow < nrows) {
            const float* xp = &X[(size_t)arow * 128 + kb * 32 + g * 8];
            x0 = *(const float4*)xp;
            x1 = *(const float4*)(xp + 4);
        }
        float xv[8] = {x0.x, x0.y, x0.z, x0.w, x1.x, x1.y, x1.z, x1.w};
        bf16x8 ahi, alo;
        #pragma unroll
        for (int j = 0; j < 8; ++j) {
            unsigned short h = f2bf_rne(xv[j]);
            ahi[j] = (short)h;
            alo[j] = (short)f2bf_rne(xv[j] - bf2f(h));
        }
        #pragma unroll
        for (int nf = 0; nf < 8; ++nf) {
            size_t off = (((size_t)kb * 8 + nf) * 64 + l) * 8;
            bf16x8 bhi = *(const bf16x8*)&hp[off];
            bf16x8 blo = *(const bf16x8*)&lp[off];
            acc[nf] = __builtin_amdgcn_mfma_f32_16x16x32_bf16(ahi, bhi, acc[nf], 0, 0, 0);
            acc[nf] = __builtin_amdgcn_mfma_f32_16x16x32_bf16(ahi, blo, acc[nf], 0, 0, 0);
            acc[nf] = __builtin_amdgcn_mfma_f32_16x16x32_bf16(alo, bhi, acc[nf], 0, 0, 0);
        }
    }

    // C/D layout: col = lane&15, row = (lane>>4)*4 + reg
    #pragma unroll
    for (int nf = 0; nf < 8; ++nf) {
        int col = nf * 16 + m15;
        float b = bias[col];
        #pragma unroll
        for (int r = 0; r < 4; ++r) {
            int row = rowbase + g * 4 + r;
            if (row < nrows)
                Out[(size_t)row * 128 + col] = acc[nf][r] + b;
        }
    }
}

// ---------------------------------------------------------------------------
// Fused GATv2 aggregation, 8 edges in flight per wave (4 groups x 2 edges).
// Wave = 1 node. Lanes: 4 groups x 16; group g owns edges pbeg+g, stride 4;
// two edges (p, p+4) loaded together per iteration, updated sequentially.
// Optional fused output projection (layer 3): out = relu(h)@Wout + bout,
// h itself never written.
// ---------------------------------------------------------------------------
__device__ __forceinline__ float lrelu(float v) {
    return v > 0.f ? v : NEG * v;
}
__device__ __forceinline__ float dot4a(float4 a, float4 x, float4 t) {
    return lrelu(a.x + x.x) * t.x + lrelu(a.y + x.y) * t.y
         + lrelu(a.z + x.z) * t.z + lrelu(a.w + x.w) * t.w;
}

__global__ __launch_bounds__(256) void gat_aggregate(
        const float* __restrict__ xl, const float* __restrict__ xr,
        const int* __restrict__ rowptr, const int* __restrict__ esrc,
        const float* __restrict__ att, const float* __restrict__ bias,
        float* __restrict__ hout, int n, int do_relu,
        const float* __restrict__ Wout, const float* __restrict__ bout,
        float* __restrict__ out4) {
    int node = (int)((blockIdx.x * blockDim.x + threadIdx.x) >> 6);
    int lane = threadIdx.x & 63;
    if (node >= n) return;
    int g  = lane >> 4;
    int gl = lane & 15;
    int c0 = gl * 4;

    const float* xrp = &xr[(size_t)node * 128];
    float4 xr0 = *(const float4*)&xrp[c0];
    float4 xr1 = *(const float4*)&xrp[64 + c0];
    float4 at0 = *(const float4*)&att[c0];
    float4 at1 = *(const float4*)&att[64 + c0];

    float m0 = -1e30f, m1 = -1e30f, s0 = 0.f, s1 = 0.f;
    float4 acc0 = make_float4(0.f, 0.f, 0.f, 0.f);
    float4 acc1 = make_float4(0.f, 0.f, 0.f, 0.f);

    int pbeg = rowptr[node], pend = rowptr[node + 1];
    for (int p = pbeg + g; p < pend; p += 8) {
        int sA = esrc[p];
        int pB = p + 4;
        bool hasB = (pB < pend);            // uniform within 16-lane group
        const float* xpA = &xl[(size_t)sA * 128];
        float4 a0A = *(const float4*)&xpA[c0];
        float4 a1A = *(const float4*)&xpA[64 + c0];
        float4 a0B = make_float4(0.f, 0.f, 0.f, 0.f), a1B = a0B;
        if (hasB) {
            int sB = esrc[pB];
            const float* xpB = &xl[(size_t)sB * 128];
            a0B = *(const float4*)&xpB[c0];
            a1B = *(const float4*)&xpB[64 + c0];
        }

        float tA0 = dot4a(a0A, xr0, at0), tA1 = dot4a(a1A, xr1, at1);
        float tB0 = dot4a(a0B, xr0, at0), tB1 = dot4a(a1B, xr1, at1);
        #pragma unroll
        for (int off = 1; off < 16; off <<= 1) {
            tA0 += __shfl_xor(tA0, off, 64);
            tA1 += __shfl_xor(tA1, off, 64);
            tB0 += __shfl_xor(tB0, off, 64);
            tB1 += __shfl_xor(tB1, off, 64);
        }

        // update with edge A
        {
            float nm0 = fmaxf(m0, tA0), nm1 = fmaxf(m1, tA1);
            float sc0 = __expf(m0 - nm0), sc1 = __expf(m1 - nm1);
            float p0  = __expf(tA0 - nm0), p1  = __expf(tA1 - nm1);
            s0 = s0 * sc0 + p0;  s1 = s1 * sc1 + p1;
            acc0.x = acc0.x * sc0 + p0 * a0A.x;  acc0.y = acc0.y * sc0 + p0 * a0A.y;
            acc0.z = acc0.z * sc0 + p0 * a0A.z;  acc0.w = acc0.w * sc0 + p0 * a0A.w;
            acc1.x = acc1.x * sc1 + p1 * a1A.x;  acc1.y = acc1.y * sc1 + p1 * a1A.y;
            acc1.z = acc1.z * sc1 + p1 * a1A.z;  acc1.w = acc1.w * sc1 + p1 * a1A.w;
            m0 = nm0; m1 = nm1;
        }
        // update with edge B
        if (hasB) {
            float nm0 = fmaxf(m0, tB0), nm1 = fmaxf(m1, tB1);
            float sc0 = __expf(m0 - nm0), sc1 = __expf(m1 - nm1);
            float p0  = __expf(tB0 - nm0), p1  = __expf(tB1 - nm1);
            s0 = s0 * sc0 + p0;  s1 = s1 * sc1 + p1;
            acc0.x = acc0.x * sc0 + p0 * a0B.x;  acc0.y = acc0.y * sc0 + p0 * a0B.y;
            acc0.z = acc0.z * sc0 + p0 * a0B.z;  acc0.w = acc0.w * sc0 + p0 * a0B.w;
            acc1.x = acc1.x * sc1 + p1 * a1B.x;  acc1.y = acc1.y * sc1 + p1 * a1B.y;
            acc1.z = acc1.z * sc1 + p1 * a1B.z;  acc1.w = acc1.w * sc1 + p1 * a1B.w;
            m0 = nm0; m1 = nm1;
        }
    }

    // flash-merge the 4 group states (xor 16 then 32)
    #pragma unroll
    for (int off = 16; off <= 32; off <<= 1) {
        float om0 = __shfl_xor(m0, off, 64), om1 = __shfl_xor(m1, off, 64);
        float os0 = __shfl_xor(s0, off, 64), os1 = __shfl_xor(s1, off, 64);
        float4 oa0, oa1;
        oa0.x = __shfl_xor(acc0.x, off, 64); oa0.y = __shfl_xor(acc0.y, off, 64);
        oa0.z = __shfl_xor(acc0.z, off, 64); oa0.w = __shfl_xor(acc0.w, off, 64);
        oa1.x = __shfl_xor(acc1.x, off, 64); oa1.y = __shfl_xor(acc1.y, off, 64);
        oa1.z = __shfl_xor(acc1.z, off, 64); oa1.w = __shfl_xor(acc1.w, off, 64);

        float nm0 = fmaxf(m0, om0), nm1 = fmaxf(m1, om1);
        float sa0 = __expf(m0 - nm0),  sb0 = __expf(om0 - nm0);
        float sa1 = __expf(m1 - nm1),  sb1 = __expf(om1 - nm1);
        s0 = s0 * sa0 + os0 * sb0;  s1 = s1 * sa1 + os1 * sb1;
        acc0.x = acc0.x * sa0 + oa0.x * sb0;  acc0.y = acc0.y * sa0 + oa0.y * sb0;
        acc0.z = acc0.z * sa0 + oa0.z * sb0;  acc0.w = acc0.w * sa0 + oa0.w * sb0;
        acc1.x = acc1.x * sa1 + oa1.x * sb1;  acc1.y = acc1.y * sa1 + oa1.y * sb1;
        acc1.z = acc1.z * sa1 + oa1.z * sb1;  acc1.w = acc1.w * sa1 + oa1.w * sb1;
        m0 = nm0; m1 = nm1;
    }

    float inv0 = 1.f / s0, inv1 = 1.f / s1;

    if (out4) {
        // fused output projection: all lanes hold the full merged state.
        float o0[4], o1[4];
        float a0v[4] = {acc0.x, acc0.y, acc0.z, acc0.w};
        float a1v[4] = {acc1.x, acc1.y, acc1.z, acc1.w};
        #pragma unroll
        for (int i = 0; i < 4; ++i) {
            o0[i] = a0v[i] * inv0 + bias[c0 + i];
            o1[i] = a1v[i] * inv1 + bias[64 + c0 + i];
            if (do_relu) { o0[i] = fmaxf(o0[i], 0.f); o1[i] = fmaxf(o1[i], 0.f); }
        }
        float p0 = 0.f, p1 = 0.f, p2 = 0.f, p3 = 0.f;
        #pragma unroll
        for (int i = 0; i < 4; ++i) {
            float4 w = *(const float4*)&Wout[(c0 + i) * 4];
            p0 += o0[i] * w.x; p1 += o0[i] * w.y; p2 += o0[i] * w.z; p3 += o0[i] * w.w;
        }
        #pragma unroll
        for (int i = 0; i < 4; ++i) {
            float4 w = *(const float4*)&Wout[(64 + c0 + i) * 4];
            p0 += o1[i] * w.x; p1 += o1[i] * w.y; p2 += o1[i] * w.z; p3 += o1[i] * w.w;
        }
        #pragma unroll
        for (int off = 1; off < 16; off <<= 1) {
            p0 += __shfl_xor(p0, off, 64);
            p1 += __shfl_xor(p1, off, 64);
            p2 += __shfl_xor(p2, off, 64);
            p3 += __shfl_xor(p3, off, 64);
        }
        if (lane == 0) {
            float4 o = make_float4(p0 + bout[0], p1 + bout[1],
                                   p2 + bout[2], p3 + bout[3]);
            *(float4*)&out4[(size_t)node * 4] = o;
        }
        return;
    }

    if (g == 0) {
        float4 vb = *(const float4*)&bias[c0];
        float4 o = make_float4(acc0.x * inv0 + vb.x, acc0.y * inv0 + vb.y,
                               acc0.z * inv0 + vb.z, acc0.w * inv0 + vb.w);
        if (do_relu) {
            o.x = fmaxf(o.x, 0.f); o.y = fmaxf(o.y, 0.f);
            o.z = fmaxf(o.z, 0.f); o.w = fmaxf(o.w, 0.f);
        }
        *(float4*)&hout[(size_t)node * 128 + c0] = o;
    } else if (g == 1) {
        float4 vb = *(const float4*)&bias[64 + c0];
        float4 o = make_float4(acc1.x * inv1 + vb.x, acc1.y * inv1 + vb.y,
                               acc1.z * inv1 + vb.z, acc1.w * inv1 + vb.w);
        if (do_relu) {
            o.x = fmaxf(o.x, 0.f); o.y = fmaxf(o.y, 0.f);
            o.z = fmaxf(o.z, 0.f); o.w = fmaxf(o.w, 0.f);
        }
        *(float4*)&hout[(size_t)node * 128 + 64 + c0] = o;
    }
}

// ---------------------------------------------------------------------------
extern "C" void kernel_launch(void* const* d_in, const int* in_sizes, int n_in,
                              void* d_out, int out_size, void* d_ws,
                              size_t ws_size, hipStream_t stream) {
    // setup_inputs order:
    //  0:x 1:edge_index 2:W1l 3:b1l 4:W1r 5:b1r 6:att1 7:bias1
    //  8:W2l 9:b2l 10:W2r 11:b2r 12:att2 13:bias2
    // 14:W3l 15:b3l 16:W3r 17:b3r 18:att3 19:bias3 20:Wout 21:bout
    const float* x    = (const float*)d_in[0];
    const int*   ei   = (const int*)  d_in[1];
    const float* W1l  = (const float*)d_in[2];
    const float* b1l  = (const float*)d_in[3];
    const float* W1r  = (const float*)d_in[4];
    const float* b1r  = (const float*)d_in[5];
    const float* att1 = (const float*)d_in[6];
    const float* bias1= (const float*)d_in[7];
    const float* W2l  = (const float*)d_in[8];
    const float* b2l  = (const float*)d_in[9];
    const float* W2r  = (const float*)d_in[10];
    const float* b2r  = (const float*)d_in[11];
    const float* att2 = (const float*)d_in[12];
    const float* bias2= (const float*)d_in[13];
    const float* W3l  = (const float*)d_in[14];
    const float* b3l  = (const float*)d_in[15];
    const float* W3r  = (const float*)d_in[16];
    const float* b3r  = (const float*)d_in[17];
    const float* att3 = (const float*)d_in[18];
    const float* bias3= (const float*)d_in[19];
    const float* Wout = (const float*)d_in[20];
    const float* bout = (const float*)d_in[21];

    int N    = in_sizes[0] / DIN;
    int E    = in_sizes[1] / 2;
    int Etot = E + N;

    float* h      = (float*)d_ws;
    float* xl     = h  + (size_t)N * HC;
    float* xr     = xl + (size_t)N * HC;
    unsigned short* whi = (unsigned short*)(xr + (size_t)N * HC);
    unsigned short* wlo = whi + 6 * 16384;
    int*   esrc   = (int*)(wlo + 6 * 16384);
    int*   rowptr = esrc + Etot;
    int*   cursor = rowptr + (((N + 1) + 3) & ~3);   // keep cursor 16B-aligned
    int*   counts = cursor + N;

    hipMemsetAsync(counts, 0, (size_t)N * sizeof(int), stream);
    hist_kernel<<<(Etot + 255) / 256, 256, 0, stream>>>(ei, E, N, counts);
    scan_kernel<<<1, 1024, 0, stream>>>(counts, rowptr, cursor, N);
    scatter_kernel<<<(Etot + 255) / 256, 256, 0, stream>>>(ei, E, N, cursor, esrc);
    prep_w<<<dim3(8, 6), 256, 0, stream>>>(W1l, W1r, W2l, W2r, W3l, W3r, whi, wlo);

    dim3 gemm_grid((N + 63) / 64, 2);
    int  agg_grid = (N + 3) / 4;

    gemm_mfma<<<gemm_grid, 256, 0, stream>>>(x, whi, wlo, 0, b1l, b1r, xl, xr, N);
    gat_aggregate<<<agg_grid, 256, 0, stream>>>(xl, xr, rowptr, esrc, att1, bias1,
                                                h, N, 1, nullptr, nullptr, nullptr);
    gemm_mfma<<<gemm_grid, 256, 0, stream>>>(h, whi, wlo, 2, b2l, b2r, xl, xr, N);
    gat_aggregate<<<agg_grid, 256, 0, stream>>>(xl, xr, rowptr, esrc, att2, bias2,
                                                h, N, 1, nullptr, nullptr, nullptr);
    gemm_mfma<<<gemm_grid, 256, 0, stream>>>(h, whi, wlo, 4, b3l, b3r, xl, xr, N);
    // layer 3: fused relu + output projection, h never materialized
    gat_aggregate<<<agg_grid, 256, 0, stream>>>(xl, xr, rowptr, esrc, att3, bias3,
                                                nullptr, N, 1, Wout, bout,
                                                (float*)d_out);
}